// Round 4
// baseline (234.069 us; speedup 1.0000x reference)
//
#include <hip/hip_runtime.h>
#include <math.h>

typedef float fvec4 __attribute__((ext_vector_type(4)));
typedef int   ivec4 __attribute__((ext_vector_type(4)));

// ---- constants ----
static constexpr double D_CUTOFF   = 7.0;
static constexpr double D_SIGMA    = 3.1589;
static constexpr double D_EPS      = 0.1852;
static constexpr double D_GAMMA    = 0.73612;
static constexpr double D_Q        = 1.1128;
static constexpr double D_OH_EQ    = 0.9419;
static constexpr double D_OH_K     = 1059.162;
static constexpr double D_OH_ALPHA = 2.287;
static constexpr double D_ANG_EQ   = 1.87448;
static constexpr double D_ANG_K    = 87.85;
static constexpr double D_SMEAR    = 1.4;
static constexpr double D_PREF     = 332.0637133;

static constexpr double D_SC6   = (D_SIGMA/D_CUTOFF)*(D_SIGMA/D_CUTOFF)*(D_SIGMA/D_CUTOFF)
                                * (D_SIGMA/D_CUTOFF)*(D_SIGMA/D_CUTOFF)*(D_SIGMA/D_CUTOFF);
static constexpr float F_SIG2      = (float)(D_SIGMA*D_SIGMA);
static constexpr float F_4EPS      = (float)(4.0*D_EPS);
static constexpr float F_LJ_SHIFT  = (float)(-4.0*D_EPS*D_SC6*(D_SC6-1.0));
static constexpr float F_Q         = (float)D_Q;
static constexpr float F_QO        = (float)(-D_Q);          // -1.1128
static constexpr float F_QH        = (float)(0.5*D_Q);       //  0.5564
static constexpr float F_PREF      = (float)D_PREF;
static constexpr float F_INV_S2S   = (float)(1.0/(1.4142135623730951*D_SMEAR));
static constexpr float F_OMG       = (float)((1.0-D_GAMMA)*0.5);
static constexpr float F_OH_EQ     = (float)D_OH_EQ;
static constexpr float F_OH_K      = (float)D_OH_K;
static constexpr float F_OH_ALPHA  = (float)D_OH_ALPHA;
static constexpr float F_ANG_EQ    = (float)D_ANG_EQ;
static constexpr float F_ANG_K     = (float)D_ANG_K;

// ---- fast erfc (A&S 7.1.26, |abs err| <= 1.5e-7) ----
__device__ __forceinline__ float fast_erfc(float x) {
    const float t = __builtin_amdgcn_rcpf(fmaf(0.3275911f, x, 1.0f));
    float p = fmaf(1.061405429f, t, -1.453152027f);
    p = fmaf(p, t, 1.421413741f);
    p = fmaf(p, t, -0.284496736f);
    p = fmaf(p, t, 0.254829592f);
    p *= t;
    return p * __expf(-x * x);
}

// ---- block reduce -> partial[slot]; last block of nb_total reduces all -> out[0] ----
__device__ __forceinline__ void reduce_and_finish(float v, float* __restrict__ partial,
        int slot, unsigned* __restrict__ counter, int nb_total, float* __restrict__ out) {
#pragma unroll
    for (int o = 32; o > 0; o >>= 1) v += __shfl_down(v, o, 64);
    __shared__ float smem[4];
    __shared__ int   is_last;
    const int lane = threadIdx.x & 63;
    const int w    = threadIdx.x >> 6;
    if (lane == 0) smem[w] = v;
    __syncthreads();
    if (threadIdx.x == 0) {
        const float t = smem[0] + smem[1] + smem[2] + smem[3];
        partial[slot] = t;
        __threadfence();                       // release partial[slot] (device scope)
        const unsigned done = atomicAdd(counter, 1u);
        is_last = (done == (unsigned)(nb_total - 1));
    }
    __syncthreads();
    if (is_last) {
        __threadfence();                       // acquire: see all partials
        float s = 0.f;
        for (int i = threadIdx.x; i < nb_total; i += 256) s += partial[i];
#pragma unroll
        for (int o = 32; o > 0; o >>= 1) s += __shfl_down(s, o, 64);
        if (lane == 0) smem[w] = s;
        __syncthreads();
        if (threadIdx.x == 0) out[0] = smem[0] + smem[1] + smem[2] + smem[3];
    }
}

__device__ __forceinline__ float bond_e(float r) {
    const float dr  = r - F_OH_EQ;
    const float adr = dr * F_OH_ALPHA;
    return 0.5f * F_OH_K * dr * dr * (1.f - adr + adr * adr * (7.f / 12.f));
}

// ---- kernel 1: per-molecule bond/bend/self energies + per-ATOM (om,q) table ----
// Neighbor-list layout: pair m (m<n_mol) is O->H1 of molecule m; pair n_mol+m is
// O->H2 (bond pairs are never cut by the 7A filter; keep-mask preserves order).
__global__ void __launch_bounds__(256) k_om(const float* __restrict__ dij,
        fvec4* __restrict__ oma, float* __restrict__ partial,
        unsigned* __restrict__ counter, int nb_total, int n_mol,
        float* __restrict__ out) {
    const int m = blockIdx.x * blockDim.x + threadIdx.x;
    float e = 0.f;
    if (m < n_mol) {
        const float* d1 = dij + 3 * (size_t)m;
        const float* d2 = dij + 3 * (size_t)(n_mol + m);
        const float x1 = d1[0], y1 = d1[1], z1 = d1[2];
        const float x2 = d2[0], y2 = d2[1], z2 = d2[2];
        const float r1 = sqrtf(x1*x1 + y1*y1 + z1*z1);
        const float r2 = sqrtf(x2*x2 + y2*y2 + z2*z2);
        e += bond_e(r1) + bond_e(r2);
        const float ca  = (x1*x2 + y1*y2 + z1*z2) * __builtin_amdgcn_rcpf(r1 * r2);
        const float da  = acosf(ca) - F_ANG_EQ;
        e += 0.5f * F_ANG_K * da * da;
        const float ox = F_OMG * (x1 + x2), oy = F_OMG * (y1 + y2), oz = F_OMG * (z1 + z2);
        oma[3 * (size_t)m + 0] = (fvec4){ox, oy, oz, F_QO};
        oma[3 * (size_t)m + 1] = (fvec4){0.f, 0.f, 0.f, F_QH};
        oma[3 * (size_t)m + 2] = (fvec4){0.f, 0.f, 0.f, F_QH};
        // minus e_self
        const float ax = x1-ox, ay = y1-oy, az = z1-oz;
        const float bx = x2-ox, by = y2-oy, bz = z2-oz;
        const float hx = x1-x2, hy = y1-y2, hz = z1-z2;
        const float inv_mh = __builtin_amdgcn_rsqf(ax*ax+ay*ay+az*az)
                           + __builtin_amdgcn_rsqf(bx*bx+by*by+bz*bz);
        const float inv_hh = __builtin_amdgcn_rsqf(hx*hx+hy*hy+hz*hz);
        e += (inv_mh * F_Q - inv_hh * 0.5f * F_Q) * (0.5f * F_Q * F_PREF);
    }
    reduce_and_finish(e, partial, blockIdx.x, counter, nb_total, out);
}

// ---- per-pair energy: 2 float4 gathers, no int div, no selects ----
__device__ __forceinline__ float pair_energy(int i, int j, float dx, float dy, float dz,
                                             const fvec4* __restrict__ oma) {
    const fvec4 oi = oma[i];
    const fvec4 oj = oma[j];
    const float sx = dx + oj.x - oi.x;
    const float sy = dy + oj.y - oi.y;
    const float sz = dz + oj.z - oi.z;
    const float r2m   = sx*sx + sy*sy + sz*sz;
    const float invrm = __builtin_amdgcn_rsqf(r2m);
    const float rm    = r2m * invrm;
    const float qq    = oi.w * oj.w;           // O-O: +1.238, O-H: -0.619, H-H: +0.310
    float e = F_PREF * qq * fast_erfc(rm * F_INV_S2S) * invrm;
    if (qq > 1.0f) {                           // O-O pair -> LJ
        const float r2 = dx*dx + dy*dy + dz*dz;
        const float s2 = F_SIG2 * __builtin_amdgcn_rcpf(r2);
        const float c6 = s2 * s2 * s2;
        e += fmaf(F_4EPS, c6 * c6 - c6, F_LJ_SHIFT);
    }
    return e;
}

// ---- kernel 2: 4 pairs/thread; nontemporal vector streams + cached oma gathers ----
__global__ void __launch_bounds__(256) k_pair(
        const int* __restrict__ ni, const int* __restrict__ nj,
        const float* __restrict__ dij, const fvec4* __restrict__ oma,
        float* __restrict__ partial, unsigned* __restrict__ counter,
        int nb_total, int slot_base, int n_pairs, float* __restrict__ out) {
    const int t = blockIdx.x * blockDim.x + threadIdx.x;
    float e = 0.f;
    const int p0 = 4 * t;
    if (p0 + 3 < n_pairs) {
        const ivec4 a  = __builtin_nontemporal_load((const ivec4*)ni + t);
        const ivec4 b  = __builtin_nontemporal_load((const ivec4*)nj + t);
        const fvec4 d0 = __builtin_nontemporal_load((const fvec4*)dij + 3 * (size_t)t + 0);
        const fvec4 d1 = __builtin_nontemporal_load((const fvec4*)dij + 3 * (size_t)t + 1);
        const fvec4 d2 = __builtin_nontemporal_load((const fvec4*)dij + 3 * (size_t)t + 2);
        e += pair_energy(a.x, b.x, d0.x, d0.y, d0.z, oma);
        e += pair_energy(a.y, b.y, d0.w, d1.x, d1.y, oma);
        e += pair_energy(a.z, b.z, d1.z, d1.w, d2.x, oma);
        e += pair_energy(a.w, b.w, d2.y, d2.z, d2.w, oma);
    } else if (p0 < n_pairs) {
        for (int p = p0; p < n_pairs; ++p)
            e += pair_energy(ni[p], nj[p],
                             dij[3 * (size_t)p], dij[3 * (size_t)p + 1],
                             dij[3 * (size_t)p + 2], oma);
    }
    reduce_and_finish(e, partial, slot_base + blockIdx.x, counter, nb_total, out);
}

extern "C" void kernel_launch(void* const* d_in, const int* in_sizes, int n_in,
                              void* d_out, int out_size, void* d_ws, size_t ws_size,
                              hipStream_t stream) {
    const float* dij = (const float*)d_in[0];
    const int* ni = (const int*)d_in[2];
    const int* nj = (const int*)d_in[3];
    float* out = (float*)d_out;

    const int n_atoms = in_sizes[1];
    const int n_pairs = in_sizes[2];
    const int n_mol   = n_atoms / 3;

    const int B = 256;
    const int NB_OM   = (n_mol + B - 1) / B;
    const int n_chunk = (n_pairs + 3) / 4;
    const int NB_PAIR = (n_chunk + B - 1) / B;
    const int nb_total = NB_OM + NB_PAIR;

    // ws layout: counter (256B slot) | oma [n_atoms float4] | partials [nb_total]
    unsigned* counter  = (unsigned*)d_ws;
    fvec4*    oma      = (fvec4*)((char*)d_ws + 256);
    float*    partials = (float*)((char*)d_ws + 256 + (size_t)n_atoms * sizeof(fvec4));

    hipMemsetAsync(counter, 0, sizeof(unsigned), stream);
    k_om  <<<NB_OM,   B, 0, stream>>>(dij, oma, partials, counter, nb_total, n_mol, out);
    k_pair<<<NB_PAIR, B, 0, stream>>>(ni, nj, dij, oma, partials, counter,
                                      nb_total, NB_OM, n_pairs, out);
}

// Round 5
// 125.189 us; speedup vs baseline: 1.8697x; 1.8697x over previous
//
#include <hip/hip_runtime.h>
#include <math.h>

typedef float fvec4 __attribute__((ext_vector_type(4)));
typedef int   ivec4 __attribute__((ext_vector_type(4)));

// ---- constants ----
static constexpr double D_CUTOFF   = 7.0;
static constexpr double D_SIGMA    = 3.1589;
static constexpr double D_EPS      = 0.1852;
static constexpr double D_GAMMA    = 0.73612;
static constexpr double D_Q        = 1.1128;
static constexpr double D_OH_EQ    = 0.9419;
static constexpr double D_OH_K     = 1059.162;
static constexpr double D_OH_ALPHA = 2.287;
static constexpr double D_ANG_EQ   = 1.87448;
static constexpr double D_ANG_K    = 87.85;
static constexpr double D_SMEAR    = 1.4;
static constexpr double D_PREF     = 332.0637133;

static constexpr double D_SC6   = (D_SIGMA/D_CUTOFF)*(D_SIGMA/D_CUTOFF)*(D_SIGMA/D_CUTOFF)
                                * (D_SIGMA/D_CUTOFF)*(D_SIGMA/D_CUTOFF)*(D_SIGMA/D_CUTOFF);
static constexpr float F_SIG2      = (float)(D_SIGMA*D_SIGMA);
static constexpr float F_4EPS      = (float)(4.0*D_EPS);
static constexpr float F_LJ_SHIFT  = (float)(-4.0*D_EPS*D_SC6*(D_SC6-1.0));
static constexpr float F_Q         = (float)D_Q;
static constexpr float F_QO        = (float)(-D_Q);          // -1.1128
static constexpr float F_QH        = (float)(0.5*D_Q);       //  0.5564
static constexpr float F_PREF      = (float)D_PREF;
static constexpr float F_INV_S2S   = (float)(1.0/(1.4142135623730951*D_SMEAR));
static constexpr float F_OMG       = (float)((1.0-D_GAMMA)*0.5);
static constexpr float F_OH_EQ     = (float)D_OH_EQ;
static constexpr float F_OH_K      = (float)D_OH_K;
static constexpr float F_OH_ALPHA  = (float)D_OH_ALPHA;
static constexpr float F_ANG_EQ    = (float)D_ANG_EQ;
static constexpr float F_ANG_K     = (float)D_ANG_K;

// ---- fast erfc (A&S 7.1.26, |abs err| <= 1.5e-7) ----
__device__ __forceinline__ float fast_erfc(float x) {
    const float t = __builtin_amdgcn_rcpf(fmaf(0.3275911f, x, 1.0f));
    float p = fmaf(1.061405429f, t, -1.453152027f);
    p = fmaf(p, t, 1.421413741f);
    p = fmaf(p, t, -0.284496736f);
    p = fmaf(p, t, 0.254829592f);
    p *= t;
    return p * __expf(-x * x);
}

// ---- block-wide sum; thread 0 stores to *dst (NO atomics, NO fences) ----
// Lesson (R1, R4): one device-scope atomic per block to a single address
// serializes at ~12 ns/RMW -> 150 us for 12K blocks. Never do that.
__device__ __forceinline__ void block_reduce_store(float v, float* dst) {
#pragma unroll
    for (int o = 32; o > 0; o >>= 1) v += __shfl_down(v, o, 64);
    __shared__ float smem[4];
    const int lane = threadIdx.x & 63;
    const int w    = threadIdx.x >> 6;
    if (lane == 0) smem[w] = v;
    __syncthreads();
    if (threadIdx.x == 0) *dst = smem[0] + smem[1] + smem[2] + smem[3];
}

__device__ __forceinline__ float bond_e(float r) {
    const float dr  = r - F_OH_EQ;
    const float adr = dr * F_OH_ALPHA;
    return 0.5f * F_OH_K * dr * dr * (1.f - adr + adr * adr * (7.f / 12.f));
}

// ---- kernel 1: per-molecule bond/bend/self energies + per-ATOM (om,q) table ----
// Neighbor-list layout: pair m (m<n_mol) is O->H1 of molecule m; pair n_mol+m is
// O->H2 (bond pairs are never cut by the 7A filter; keep-mask preserves order).
__global__ void __launch_bounds__(256) k_om(const float* __restrict__ dij,
        fvec4* __restrict__ oma, float* __restrict__ partial, int n_mol) {
    const int m = blockIdx.x * blockDim.x + threadIdx.x;
    float e = 0.f;
    if (m < n_mol) {
        const float* d1 = dij + 3 * (size_t)m;
        const float* d2 = dij + 3 * (size_t)(n_mol + m);
        const float x1 = d1[0], y1 = d1[1], z1 = d1[2];
        const float x2 = d2[0], y2 = d2[1], z2 = d2[2];
        const float r1 = sqrtf(x1*x1 + y1*y1 + z1*z1);
        const float r2 = sqrtf(x2*x2 + y2*y2 + z2*z2);
        e += bond_e(r1) + bond_e(r2);
        const float ca  = (x1*x2 + y1*y2 + z1*z2) * __builtin_amdgcn_rcpf(r1 * r2);
        const float da  = acosf(ca) - F_ANG_EQ;
        e += 0.5f * F_ANG_K * da * da;
        const float ox = F_OMG * (x1 + x2), oy = F_OMG * (y1 + y2), oz = F_OMG * (z1 + z2);
        oma[3 * (size_t)m + 0] = (fvec4){ox, oy, oz, F_QO};
        oma[3 * (size_t)m + 1] = (fvec4){0.f, 0.f, 0.f, F_QH};
        oma[3 * (size_t)m + 2] = (fvec4){0.f, 0.f, 0.f, F_QH};
        // minus e_self
        const float ax = x1-ox, ay = y1-oy, az = z1-oz;
        const float bx = x2-ox, by = y2-oy, bz = z2-oz;
        const float hx = x1-x2, hy = y1-y2, hz = z1-z2;
        const float inv_mh = __builtin_amdgcn_rsqf(ax*ax+ay*ay+az*az)
                           + __builtin_amdgcn_rsqf(bx*bx+by*by+bz*bz);
        const float inv_hh = __builtin_amdgcn_rsqf(hx*hx+hy*hy+hz*hz);
        e += (inv_mh * F_Q - inv_hh * 0.5f * F_Q) * (0.5f * F_Q * F_PREF);
    }
    block_reduce_store(e, partial + blockIdx.x);
}

// ---- per-pair energy: 2 float4 gathers, no int div, no selects ----
__device__ __forceinline__ float pair_energy(int i, int j, float dx, float dy, float dz,
                                             const fvec4* __restrict__ oma) {
    const fvec4 oi = oma[i];
    const fvec4 oj = oma[j];
    const float sx = dx + oj.x - oi.x;
    const float sy = dy + oj.y - oi.y;
    const float sz = dz + oj.z - oi.z;
    const float r2m   = sx*sx + sy*sy + sz*sz;
    const float invrm = __builtin_amdgcn_rsqf(r2m);
    const float rm    = r2m * invrm;
    const float qq    = oi.w * oj.w;           // O-O: +1.238, O-H: -0.619, H-H: +0.310
    float e = F_PREF * qq * fast_erfc(rm * F_INV_S2S) * invrm;
    if (qq > 1.0f) {                           // O-O pair -> LJ
        const float r2 = dx*dx + dy*dy + dz*dz;
        const float s2 = F_SIG2 * __builtin_amdgcn_rcpf(r2);
        const float c6 = s2 * s2 * s2;
        e += fmaf(F_4EPS, c6 * c6 - c6, F_LJ_SHIFT);
    }
    return e;
}

// ---- kernel 2: 4 pairs/thread; nontemporal vector streams + cached oma gathers ----
__global__ void __launch_bounds__(256) k_pair(
        const int* __restrict__ ni, const int* __restrict__ nj,
        const float* __restrict__ dij, const fvec4* __restrict__ oma,
        float* __restrict__ partial, int n_pairs) {
    const int t = blockIdx.x * blockDim.x + threadIdx.x;
    float e = 0.f;
    const int p0 = 4 * t;
    if (p0 + 3 < n_pairs) {
        const ivec4 a  = __builtin_nontemporal_load((const ivec4*)ni + t);
        const ivec4 b  = __builtin_nontemporal_load((const ivec4*)nj + t);
        const fvec4 d0 = __builtin_nontemporal_load((const fvec4*)dij + 3 * (size_t)t + 0);
        const fvec4 d1 = __builtin_nontemporal_load((const fvec4*)dij + 3 * (size_t)t + 1);
        const fvec4 d2 = __builtin_nontemporal_load((const fvec4*)dij + 3 * (size_t)t + 2);
        e += pair_energy(a.x, b.x, d0.x, d0.y, d0.z, oma);
        e += pair_energy(a.y, b.y, d0.w, d1.x, d1.y, oma);
        e += pair_energy(a.z, b.z, d1.z, d1.w, d2.x, oma);
        e += pair_energy(a.w, b.w, d2.y, d2.z, d2.w, oma);
    } else if (p0 < n_pairs) {
        for (int p = p0; p < n_pairs; ++p)
            e += pair_energy(ni[p], nj[p],
                             dij[3 * (size_t)p], dij[3 * (size_t)p + 1],
                             dij[3 * (size_t)p + 2], oma);
    }
    block_reduce_store(e, partial + blockIdx.x);
}

// ---- kernel 3: final reduction of block partials -> d_out[0] ----
__global__ void k_reduce(const float* __restrict__ partial, int n, float* __restrict__ out) {
    float v = 0.f;
    for (int i = threadIdx.x; i < n; i += blockDim.x) v += partial[i];
#pragma unroll
    for (int o = 32; o > 0; o >>= 1) v += __shfl_down(v, o, 64);
    __shared__ float smem[4];
    const int lane = threadIdx.x & 63;
    const int w    = threadIdx.x >> 6;
    if (lane == 0) smem[w] = v;
    __syncthreads();
    if (threadIdx.x == 0) out[0] = smem[0] + smem[1] + smem[2] + smem[3];
}

extern "C" void kernel_launch(void* const* d_in, const int* in_sizes, int n_in,
                              void* d_out, int out_size, void* d_ws, size_t ws_size,
                              hipStream_t stream) {
    const float* dij = (const float*)d_in[0];
    const int* ni = (const int*)d_in[2];
    const int* nj = (const int*)d_in[3];
    float* out = (float*)d_out;

    const int n_atoms = in_sizes[1];
    const int n_pairs = in_sizes[2];
    const int n_mol   = n_atoms / 3;

    const int B = 256;
    const int NB_OM   = (n_mol + B - 1) / B;
    const int n_chunk = (n_pairs + 3) / 4;
    const int NB_PAIR = (n_chunk + B - 1) / B;

    // ws layout: oma [n_atoms float4] | partials [NB_OM + NB_PAIR floats]
    fvec4* oma      = (fvec4*)d_ws;
    float* partials = (float*)((char*)d_ws + (size_t)n_atoms * sizeof(fvec4));

    k_om    <<<NB_OM,   B, 0, stream>>>(dij, oma, partials, n_mol);
    k_pair  <<<NB_PAIR, B, 0, stream>>>(ni, nj, dij, oma, partials + NB_OM, n_pairs);
    k_reduce<<<1,       B, 0, stream>>>(partials, NB_OM + NB_PAIR, out);
}

// Round 6
// 113.188 us; speedup vs baseline: 2.0680x; 1.1060x over previous
//
#include <hip/hip_runtime.h>
#include <math.h>

typedef float fvec4 __attribute__((ext_vector_type(4)));
typedef int   ivec4 __attribute__((ext_vector_type(4)));

// ---- constants ----
static constexpr double D_CUTOFF   = 7.0;
static constexpr double D_SIGMA    = 3.1589;
static constexpr double D_EPS      = 0.1852;
static constexpr double D_GAMMA    = 0.73612;
static constexpr double D_Q        = 1.1128;
static constexpr double D_OH_EQ    = 0.9419;
static constexpr double D_OH_K     = 1059.162;
static constexpr double D_OH_ALPHA = 2.287;
static constexpr double D_ANG_EQ   = 1.87448;
static constexpr double D_ANG_K    = 87.85;
static constexpr double D_SMEAR    = 1.4;
static constexpr double D_PREF     = 332.0637133;

static constexpr double D_SC6   = (D_SIGMA/D_CUTOFF)*(D_SIGMA/D_CUTOFF)*(D_SIGMA/D_CUTOFF)
                                * (D_SIGMA/D_CUTOFF)*(D_SIGMA/D_CUTOFF)*(D_SIGMA/D_CUTOFF);
static constexpr float F_SIG2      = (float)(D_SIGMA*D_SIGMA);
static constexpr float F_4EPS      = (float)(4.0*D_EPS);
static constexpr float F_LJ_SHIFT  = (float)(-4.0*D_EPS*D_SC6*(D_SC6-1.0));
static constexpr float F_Q         = (float)D_Q;
static constexpr float F_QO        = (float)(-D_Q);          // -1.1128
static constexpr float F_QH        = (float)(0.5*D_Q);       //  0.5564
static constexpr float F_PREF      = (float)D_PREF;
static constexpr float F_INV_S2S   = (float)(1.0/(1.4142135623730951*D_SMEAR));
static constexpr float F_OMG       = (float)((1.0-D_GAMMA)*0.5);
static constexpr float F_OH_EQ     = (float)D_OH_EQ;
static constexpr float F_OH_K      = (float)D_OH_K;
static constexpr float F_OH_ALPHA  = (float)D_OH_ALPHA;
static constexpr float F_ANG_EQ    = (float)D_ANG_EQ;
static constexpr float F_ANG_K     = (float)D_ANG_K;

// ---- fast erfc (A&S 7.1.26, |abs err| <= 1.5e-7) ----
__device__ __forceinline__ float fast_erfc(float x) {
    const float t = __builtin_amdgcn_rcpf(fmaf(0.3275911f, x, 1.0f));
    float p = fmaf(1.061405429f, t, -1.453152027f);
    p = fmaf(p, t, 1.421413741f);
    p = fmaf(p, t, -0.284496736f);
    p = fmaf(p, t, 0.254829592f);
    p *= t;
    return p * __expf(-x * x);
}

// ---- block-wide sum; thread 0 stores to *dst (NO atomics, NO fences) ----
// Lesson (R1, R4): one device-scope atomic per block to a single address
// serializes at ~12 ns/RMW -> 150 us for 12K blocks. Never do that.
__device__ __forceinline__ void block_reduce_store(float v, float* dst) {
#pragma unroll
    for (int o = 32; o > 0; o >>= 1) v += __shfl_down(v, o, 64);
    __shared__ float smem[4];
    const int lane = threadIdx.x & 63;
    const int w    = threadIdx.x >> 6;
    if (lane == 0) smem[w] = v;
    __syncthreads();
    if (threadIdx.x == 0) *dst = smem[0] + smem[1] + smem[2] + smem[3];
}

__device__ __forceinline__ float bond_e(float r) {
    const float dr  = r - F_OH_EQ;
    const float adr = dr * F_OH_ALPHA;
    return 0.5f * F_OH_K * dr * dr * (1.f - adr + adr * adr * (7.f / 12.f));
}

// ---- kernel 1: per-molecule bond/bend/self energies + per-ATOM (om,q) table ----
// Neighbor-list layout: pair m (m<n_mol) is O->H1 of molecule m; pair n_mol+m is
// O->H2 (bond pairs are never cut by the 7A filter; keep-mask preserves order).
__global__ void __launch_bounds__(256) k_om(const float* __restrict__ dij,
        fvec4* __restrict__ oma, float* __restrict__ partial, int n_mol) {
    const int m = blockIdx.x * blockDim.x + threadIdx.x;
    float e = 0.f;
    if (m < n_mol) {
        const float* d1 = dij + 3 * (size_t)m;
        const float* d2 = dij + 3 * (size_t)(n_mol + m);
        const float x1 = d1[0], y1 = d1[1], z1 = d1[2];
        const float x2 = d2[0], y2 = d2[1], z2 = d2[2];
        const float r1 = sqrtf(x1*x1 + y1*y1 + z1*z1);
        const float r2 = sqrtf(x2*x2 + y2*y2 + z2*z2);
        e += bond_e(r1) + bond_e(r2);
        const float ca  = (x1*x2 + y1*y2 + z1*z2) * __builtin_amdgcn_rcpf(r1 * r2);
        const float da  = acosf(ca) - F_ANG_EQ;
        e += 0.5f * F_ANG_K * da * da;
        const float ox = F_OMG * (x1 + x2), oy = F_OMG * (y1 + y2), oz = F_OMG * (z1 + z2);
        oma[3 * (size_t)m + 0] = (fvec4){ox, oy, oz, F_QO};
        oma[3 * (size_t)m + 1] = (fvec4){0.f, 0.f, 0.f, F_QH};
        oma[3 * (size_t)m + 2] = (fvec4){0.f, 0.f, 0.f, F_QH};
        // minus e_self
        const float ax = x1-ox, ay = y1-oy, az = z1-oz;
        const float bx = x2-ox, by = y2-oy, bz = z2-oz;
        const float hx = x1-x2, hy = y1-y2, hz = z1-z2;
        const float inv_mh = __builtin_amdgcn_rsqf(ax*ax+ay*ay+az*az)
                           + __builtin_amdgcn_rsqf(bx*bx+by*by+bz*bz);
        const float inv_hh = __builtin_amdgcn_rsqf(hx*hx+hy*hy+hz*hz);
        e += (inv_mh * F_Q - inv_hh * 0.5f * F_Q) * (0.5f * F_Q * F_PREF);
    }
    block_reduce_store(e, partial + blockIdx.x);
}

// ---- per-pair energy: 2 float4 gathers, no int div, no selects ----
__device__ __forceinline__ float pair_energy(int i, int j, float dx, float dy, float dz,
                                             const fvec4* __restrict__ oma) {
    const fvec4 oi = oma[i];
    const fvec4 oj = oma[j];
    const float sx = dx + oj.x - oi.x;
    const float sy = dy + oj.y - oi.y;
    const float sz = dz + oj.z - oi.z;
    const float r2m   = sx*sx + sy*sy + sz*sz;
    const float invrm = __builtin_amdgcn_rsqf(r2m);
    const float rm    = r2m * invrm;
    const float qq    = oi.w * oj.w;           // O-O: +1.238, O-H: -0.619, H-H: +0.310
    float e = F_PREF * qq * fast_erfc(rm * F_INV_S2S) * invrm;
    if (qq > 1.0f) {                           // O-O pair -> LJ
        const float r2 = dx*dx + dy*dy + dz*dz;
        const float s2 = F_SIG2 * __builtin_amdgcn_rcpf(r2);
        const float c6 = s2 * s2 * s2;
        e += fmaf(F_4EPS, c6 * c6 - c6, F_LJ_SHIFT);
    }
    return e;
}

// ---- kernel 2: 8 pairs/thread; all stream loads issued up-front (MLP),
//      plain (cached) loads — the harness restore leaves inputs L2/L3-hot ----
__global__ void __launch_bounds__(256) k_pair(
        const int* __restrict__ ni, const int* __restrict__ nj,
        const float* __restrict__ dij, const fvec4* __restrict__ oma,
        float* __restrict__ partial, int n_pairs) {
    const int t = blockIdx.x * blockDim.x + threadIdx.x;
    float e = 0.f;
    const int p0 = 8 * t;
    if (p0 + 7 < n_pairs) {
        const ivec4 a0 = ((const ivec4*)ni)[2 * (size_t)t + 0];
        const ivec4 a1 = ((const ivec4*)ni)[2 * (size_t)t + 1];
        const ivec4 b0 = ((const ivec4*)nj)[2 * (size_t)t + 0];
        const ivec4 b1 = ((const ivec4*)nj)[2 * (size_t)t + 1];
        const fvec4 d0 = ((const fvec4*)dij)[6 * (size_t)t + 0];
        const fvec4 d1 = ((const fvec4*)dij)[6 * (size_t)t + 1];
        const fvec4 d2 = ((const fvec4*)dij)[6 * (size_t)t + 2];
        const fvec4 d3 = ((const fvec4*)dij)[6 * (size_t)t + 3];
        const fvec4 d4 = ((const fvec4*)dij)[6 * (size_t)t + 4];
        const fvec4 d5 = ((const fvec4*)dij)[6 * (size_t)t + 5];
        e += pair_energy(a0.x, b0.x, d0.x, d0.y, d0.z, oma);
        e += pair_energy(a0.y, b0.y, d0.w, d1.x, d1.y, oma);
        e += pair_energy(a0.z, b0.z, d1.z, d1.w, d2.x, oma);
        e += pair_energy(a0.w, b0.w, d2.y, d2.z, d2.w, oma);
        e += pair_energy(a1.x, b1.x, d3.x, d3.y, d3.z, oma);
        e += pair_energy(a1.y, b1.y, d3.w, d4.x, d4.y, oma);
        e += pair_energy(a1.z, b1.z, d4.z, d4.w, d5.x, oma);
        e += pair_energy(a1.w, b1.w, d5.y, d5.z, d5.w, oma);
    } else if (p0 < n_pairs) {
        for (int p = p0; p < n_pairs; ++p)
            e += pair_energy(ni[p], nj[p],
                             dij[3 * (size_t)p], dij[3 * (size_t)p + 1],
                             dij[3 * (size_t)p + 2], oma);
    }
    block_reduce_store(e, partial + blockIdx.x);
}

// ---- kernel 3: final reduction of block partials -> d_out[0] (float4 reads) ----
__global__ void k_reduce(const float* __restrict__ partial, int n, float* __restrict__ out) {
    float v = 0.f;
    const int n4 = n >> 2;
    const fvec4* p4 = (const fvec4*)partial;
    for (int i = threadIdx.x; i < n4; i += blockDim.x) {
        const fvec4 x = p4[i];
        v += x.x + x.y + x.z + x.w;
    }
    for (int i = 4 * n4 + threadIdx.x; i < n; i += blockDim.x) v += partial[i];
#pragma unroll
    for (int o = 32; o > 0; o >>= 1) v += __shfl_down(v, o, 64);
    __shared__ float smem[4];
    const int lane = threadIdx.x & 63;
    const int w    = threadIdx.x >> 6;
    if (lane == 0) smem[w] = v;
    __syncthreads();
    if (threadIdx.x == 0) out[0] = smem[0] + smem[1] + smem[2] + smem[3];
}

extern "C" void kernel_launch(void* const* d_in, const int* in_sizes, int n_in,
                              void* d_out, int out_size, void* d_ws, size_t ws_size,
                              hipStream_t stream) {
    const float* dij = (const float*)d_in[0];
    const int* ni = (const int*)d_in[2];
    const int* nj = (const int*)d_in[3];
    float* out = (float*)d_out;

    const int n_atoms = in_sizes[1];
    const int n_pairs = in_sizes[2];
    const int n_mol   = n_atoms / 3;

    const int B = 256;
    const int NB_OM   = (n_mol + B - 1) / B;
    const int n_chunk = (n_pairs + 7) / 8;
    const int NB_PAIR = (n_chunk + B - 1) / B;

    // ws layout: oma [n_atoms float4] | partials [NB_OM + NB_PAIR floats]
    fvec4* oma      = (fvec4*)d_ws;
    float* partials = (float*)((char*)d_ws + (size_t)n_atoms * sizeof(fvec4));

    k_om    <<<NB_OM,   B, 0, stream>>>(dij, oma, partials, n_mol);
    k_pair  <<<NB_PAIR, B, 0, stream>>>(ni, nj, dij, oma, partials + NB_OM, n_pairs);
    k_reduce<<<1,       B, 0, stream>>>(partials, NB_OM + NB_PAIR, out);
}

// Round 7
// 102.157 us; speedup vs baseline: 2.2913x; 1.1080x over previous
//
#include <hip/hip_runtime.h>
#include <math.h>

typedef float fvec4 __attribute__((ext_vector_type(4)));
typedef int   ivec4 __attribute__((ext_vector_type(4)));

// ---- constants ----
static constexpr double D_CUTOFF   = 7.0;
static constexpr double D_SIGMA    = 3.1589;
static constexpr double D_EPS      = 0.1852;
static constexpr double D_GAMMA    = 0.73612;
static constexpr double D_Q        = 1.1128;
static constexpr double D_OH_EQ    = 0.9419;
static constexpr double D_OH_K     = 1059.162;
static constexpr double D_OH_ALPHA = 2.287;
static constexpr double D_ANG_EQ   = 1.87448;
static constexpr double D_ANG_K    = 87.85;
static constexpr double D_SMEAR    = 1.4;
static constexpr double D_PREF     = 332.0637133;

static constexpr double D_SC6   = (D_SIGMA/D_CUTOFF)*(D_SIGMA/D_CUTOFF)*(D_SIGMA/D_CUTOFF)
                                * (D_SIGMA/D_CUTOFF)*(D_SIGMA/D_CUTOFF)*(D_SIGMA/D_CUTOFF);
static constexpr float F_SIG2      = (float)(D_SIGMA*D_SIGMA);
static constexpr float F_4EPS      = (float)(4.0*D_EPS);
static constexpr float F_LJ_SHIFT  = (float)(-4.0*D_EPS*D_SC6*(D_SC6-1.0));
static constexpr float F_Q         = (float)D_Q;
static constexpr float F_QO        = (float)(-D_Q);          // -1.1128
static constexpr float F_QH        = (float)(0.5*D_Q);       //  0.5564
static constexpr float F_PREF      = (float)D_PREF;
static constexpr float F_INV_S2S   = (float)(1.0/(1.4142135623730951*D_SMEAR));
static constexpr float F_OMG       = (float)((1.0-D_GAMMA)*0.5);
static constexpr float F_OH_EQ     = (float)D_OH_EQ;
static constexpr float F_OH_K      = (float)D_OH_K;
static constexpr float F_OH_ALPHA  = (float)D_OH_ALPHA;
static constexpr float F_ANG_EQ    = (float)D_ANG_EQ;
static constexpr float F_ANG_K     = (float)D_ANG_K;

// ---- fast erfc (A&S 7.1.26, |abs err| <= 1.5e-7) ----
__device__ __forceinline__ float fast_erfc(float x) {
    const float t = __builtin_amdgcn_rcpf(fmaf(0.3275911f, x, 1.0f));
    float p = fmaf(1.061405429f, t, -1.453152027f);
    p = fmaf(p, t, 1.421413741f);
    p = fmaf(p, t, -0.284496736f);
    p = fmaf(p, t, 0.254829592f);
    p *= t;
    return p * __expf(-x * x);
}

// ---- block-wide sum; thread 0 stores to *dst (NO atomics, NO fences) ----
// Lesson (R1, R4): one device-scope atomic per block to a single address
// serializes at ~12 ns/RMW -> 150 us for 12K blocks. Never do that.
__device__ __forceinline__ void block_reduce_store(float v, float* dst) {
#pragma unroll
    for (int o = 32; o > 0; o >>= 1) v += __shfl_down(v, o, 64);
    __shared__ float smem[4];
    const int lane = threadIdx.x & 63;
    const int w    = threadIdx.x >> 6;
    if (lane == 0) smem[w] = v;
    __syncthreads();
    if (threadIdx.x == 0) *dst = smem[0] + smem[1] + smem[2] + smem[3];
}

__device__ __forceinline__ float bond_e(float r) {
    const float dr  = r - F_OH_EQ;
    const float adr = dr * F_OH_ALPHA;
    return 0.5f * F_OH_K * dr * dr * (1.f - adr + adr * adr * (7.f / 12.f));
}

// ---- kernel 1: per-molecule bond/bend/self energies + per-MOLECULE om table ----
// (221 KB table: 3x smaller gather working set than per-atom -> better L1/L2 hit.)
// Neighbor-list layout: pair m (m<n_mol) is O->H1 of molecule m; pair n_mol+m is
// O->H2 (bond pairs are never cut by the 7A filter; keep-mask preserves order).
__global__ void __launch_bounds__(256) k_om(const float* __restrict__ dij,
        fvec4* __restrict__ om, float* __restrict__ partial, int n_mol) {
    const int m = blockIdx.x * blockDim.x + threadIdx.x;
    float e = 0.f;
    if (m < n_mol) {
        const float* d1 = dij + 3 * (size_t)m;
        const float* d2 = dij + 3 * (size_t)(n_mol + m);
        const float x1 = d1[0], y1 = d1[1], z1 = d1[2];
        const float x2 = d2[0], y2 = d2[1], z2 = d2[2];
        const float r1 = sqrtf(x1*x1 + y1*y1 + z1*z1);
        const float r2 = sqrtf(x2*x2 + y2*y2 + z2*z2);
        e += bond_e(r1) + bond_e(r2);
        const float ca  = (x1*x2 + y1*y2 + z1*z2) * __builtin_amdgcn_rcpf(r1 * r2);
        const float da  = acosf(ca) - F_ANG_EQ;
        e += 0.5f * F_ANG_K * da * da;
        const float ox = F_OMG * (x1 + x2), oy = F_OMG * (y1 + y2), oz = F_OMG * (z1 + z2);
        om[m] = (fvec4){ox, oy, oz, 0.f};
        // minus e_self
        const float ax = x1-ox, ay = y1-oy, az = z1-oz;
        const float bx = x2-ox, by = y2-oy, bz = z2-oz;
        const float hx = x1-x2, hy = y1-y2, hz = z1-z2;
        const float inv_mh = __builtin_amdgcn_rsqf(ax*ax+ay*ay+az*az)
                           + __builtin_amdgcn_rsqf(bx*bx+by*by+bz*bz);
        const float inv_hh = __builtin_amdgcn_rsqf(hx*hx+hy*hy+hz*hz);
        e += (inv_mh * F_Q - inv_hh * 0.5f * F_Q) * (0.5f * F_Q * F_PREF);
    }
    block_reduce_store(e, partial + blockIdx.x);
}

// ---- per-pair energy: 2 float4 gathers from the 221 KB molecule table,
//      branchless H-masking, q from atom parity (magic-mul /3, no real div) ----
__device__ __forceinline__ float pair_energy(int i, int j, float dx, float dy, float dz,
                                             const fvec4* __restrict__ om) {
    const unsigned ui = (unsigned)i, uj = (unsigned)j;
    const unsigned mi = ui / 3u, mj = uj / 3u;
    const bool iO = (ui == 3u * mi);
    const bool jO = (uj == 3u * mj);
    const fvec4 oi = om[mi];
    const fvec4 oj = om[mj];
    const float fi = iO ? 1.f : 0.f;
    const float fj = jO ? 1.f : 0.f;
    const float sx = fmaf(-fi, oi.x, fmaf(fj, oj.x, dx));
    const float sy = fmaf(-fi, oi.y, fmaf(fj, oj.y, dy));
    const float sz = fmaf(-fi, oi.z, fmaf(fj, oj.z, dz));
    const float r2m   = sx*sx + sy*sy + sz*sz;
    const float invrm = __builtin_amdgcn_rsqf(r2m);
    const float rm    = r2m * invrm;
    const float qq    = (iO ? F_QO : F_QH) * (jO ? F_QO : F_QH);
    float e = F_PREF * qq * fast_erfc(rm * F_INV_S2S) * invrm;
    if (qq > 1.0f) {                           // O-O pair -> LJ
        const float r2 = dx*dx + dy*dy + dz*dz;
        const float s2 = F_SIG2 * __builtin_amdgcn_rcpf(r2);
        const float c6 = s2 * s2 * s2;
        e += fmaf(F_4EPS, c6 * c6 - c6, F_LJ_SHIFT);
    }
    return e;
}

// ---- kernel 2: 4 pairs/thread (blocked-4: best measured gather locality),
//      vectorized streams, plain cached loads ----
__global__ void __launch_bounds__(256) k_pair(
        const int* __restrict__ ni, const int* __restrict__ nj,
        const float* __restrict__ dij, const fvec4* __restrict__ om,
        float* __restrict__ partial, int n_pairs) {
    const int t = blockIdx.x * blockDim.x + threadIdx.x;
    float e = 0.f;
    const int p0 = 4 * t;
    if (p0 + 3 < n_pairs) {
        const ivec4 a  = ((const ivec4*)ni)[t];
        const ivec4 b  = ((const ivec4*)nj)[t];
        const fvec4 d0 = ((const fvec4*)dij)[3 * (size_t)t + 0];
        const fvec4 d1 = ((const fvec4*)dij)[3 * (size_t)t + 1];
        const fvec4 d2 = ((const fvec4*)dij)[3 * (size_t)t + 2];
        e += pair_energy(a.x, b.x, d0.x, d0.y, d0.z, om);
        e += pair_energy(a.y, b.y, d0.w, d1.x, d1.y, om);
        e += pair_energy(a.z, b.z, d1.z, d1.w, d2.x, om);
        e += pair_energy(a.w, b.w, d2.y, d2.z, d2.w, om);
    } else if (p0 < n_pairs) {
        for (int p = p0; p < n_pairs; ++p)
            e += pair_energy(ni[p], nj[p],
                             dij[3 * (size_t)p], dij[3 * (size_t)p + 1],
                             dij[3 * (size_t)p + 2], om);
    }
    block_reduce_store(e, partial + blockIdx.x);
}

// ---- kernel 3: final reduction of block partials -> d_out[0] (float4 reads) ----
__global__ void k_reduce(const float* __restrict__ partial, int n, float* __restrict__ out) {
    float v = 0.f;
    const int n4 = n >> 2;
    const fvec4* p4 = (const fvec4*)partial;
    for (int i = threadIdx.x; i < n4; i += blockDim.x) {
        const fvec4 x = p4[i];
        v += x.x + x.y + x.z + x.w;
    }
    for (int i = 4 * n4 + threadIdx.x; i < n; i += blockDim.x) v += partial[i];
#pragma unroll
    for (int o = 32; o > 0; o >>= 1) v += __shfl_down(v, o, 64);
    __shared__ float smem[4];
    const int lane = threadIdx.x & 63;
    const int w    = threadIdx.x >> 6;
    if (lane == 0) smem[w] = v;
    __syncthreads();
    if (threadIdx.x == 0) out[0] = smem[0] + smem[1] + smem[2] + smem[3];
}

extern "C" void kernel_launch(void* const* d_in, const int* in_sizes, int n_in,
                              void* d_out, int out_size, void* d_ws, size_t ws_size,
                              hipStream_t stream) {
    const float* dij = (const float*)d_in[0];
    const int* ni = (const int*)d_in[2];
    const int* nj = (const int*)d_in[3];
    float* out = (float*)d_out;

    const int n_atoms = in_sizes[1];
    const int n_pairs = in_sizes[2];
    const int n_mol   = n_atoms / 3;

    const int B = 256;
    const int NB_OM   = (n_mol + B - 1) / B;
    const int n_chunk = (n_pairs + 3) / 4;
    const int NB_PAIR = (n_chunk + B - 1) / B;

    // ws layout: om [n_mol float4] | partials [NB_OM + NB_PAIR floats]
    fvec4* om       = (fvec4*)d_ws;
    float* partials = (float*)((char*)d_ws + (size_t)n_mol * sizeof(fvec4));

    k_om    <<<NB_OM,   B, 0, stream>>>(dij, om, partials, n_mol);
    k_pair  <<<NB_PAIR, B, 0, stream>>>(ni, nj, dij, om, partials + NB_OM, n_pairs);
    k_reduce<<<1,       B, 0, stream>>>(partials, NB_OM + NB_PAIR, out);
}